// Round 9
// baseline (1234.325 us; speedup 1.0000x reference)
//
#include <hip/hip_runtime.h>
#include <hip/hip_cooperative_groups.h>
#include <hip/hip_bf16.h>
#include <math.h>

namespace cg = cooperative_groups;

#define B_   8
#define E_   256
#define N_   32
#define D_   512
#define RD_  768
#define R_   2000
#define L_   2
#define K_   8
#define M_   32
#define H_   8
#define DH_  64
#define HL_  4096

typedef float f32x4 __attribute__((ext_vector_type(4)));
typedef __bf16 bf16x8 __attribute__((ext_vector_type(8)));
typedef const __attribute__((address_space(1))) void GVoid;
typedef __attribute__((address_space(3))) void LVoid;

__device__ __forceinline__ float gelu_exact(float x) {
    return 0.5f * x * (1.0f + erff(x * 0.70710678118654752f));
}
__device__ __forceinline__ unsigned short f2bf(float x) {
    return __hip_bfloat16_raw(__float2bfloat16(x)).x;
}

struct AllArgs {
    // prep: straight conversions
    const float* csrc[9]; unsigned short* cdst[9]; int cum4[10];
    int nb_cvt, total4, nb_prep;
    // prep: misc
    const float* ly_vw; unsigned short* vwT;
    const float* ly_ow; const float* ly_vb; const float* ly_ob; float* bfuse;
    const float* t_kb; const float* t_vb; float* kvb;
    const float* edge_mask; float* flags;
    const float* mem_q; const float* t_qw; const float* t_qb; float* qbuf;
    // pipeline
    const int* eids; const int* nids;
    unsigned short* rel_bf; unsigned short* rpw_bf; const float* rp_b; float* proj;
    unsigned short* agg_bf; float* states; unsigned short* states_bf;
    unsigned short* ow_bf; unsigned short* wfuse;
    float* attnall;
    const float* n1g; const float* n1b; const float* n2g; const float* n2b;
    unsigned short* w1; const float* b1; unsigned short* w2; const float* b2;
    unsigned short* ff1; float* tmpB;
    unsigned short* kvw; float* kvbuf;
    unsigned short* membf; unsigned short* toww; const float* t_ob; unsigned short* mem2;
    unsigned short* pw; const float* proj_b; float* outp;
};

// ---------------------------------------------------------------------------
// bf16 MFMA GEMM stage (m97-style), grid-stride over tiles (+ optional z batch).
// BK=64, global_load_lds width=16, XOR chunk-swizzled LDS. TM in {32,64}.
// N%TN==0, K%64==0, A rows allocated up to ceil(M/TM)*TM. Store guard r<M.
// ---------------------------------------------------------------------------
template <int TM, int TN, int GELU_, int OBF_, int BIAS_, int FLAGS_>
__device__ __forceinline__ void gemm_stage(const unsigned short* __restrict__ A,
                                           const unsigned short* __restrict__ W,
                                           const float* __restrict__ bias,
                                           void* __restrict__ Cv,
                                           int M, int N, int K,
                                           const float* __restrict__ rowflag,
                                           int zn, size_t sA, size_t sW, size_t sC,
                                           unsigned char* SM) {
    constexpr int WTM = TM / 2, WTN = TN / 2;
    constexpr int RM = WTM / 16, RN = WTN / 16;
    constexpr int AI = TM / 32, BI = TN / 32;
    unsigned short* As = (unsigned short*)SM;
    unsigned short* Bs = (unsigned short*)(SM + 8192);

    const int tid = threadIdx.x;
    const int wave = tid >> 6, lane = tid & 63;
    const int quad = lane >> 4, l16 = lane & 15;
    const int wm = wave >> 1, wn = wave & 1;
    const int sub = lane >> 3;
    const int cpr = (lane & 7) ^ sub;
    const int ntx = N / TN;
    const int nty = (M + TM - 1) / TM;
    const int ntiles = ntx * nty * zn;

    for (int t0 = blockIdx.x; t0 < ntiles; t0 += gridDim.x) {
        int z = t0 / (ntx * nty);
        int tt = t0 - z * (ntx * nty);
        int bn = (tt % ntx) * TN, bm = (tt / ntx) * TM;
        const unsigned short* Az = A + (size_t)z * sA;
        const unsigned short* Wz = W + (size_t)z * sW;

        f32x4 acc[RM][RN];
#pragma unroll
        for (int i = 0; i < RM; i++)
#pragma unroll
            for (int j = 0; j < RN; j++) acc[i][j] = (f32x4){0.f, 0.f, 0.f, 0.f};

        for (int k0 = 0; k0 < K; k0 += 64) {
            __syncthreads();
#pragma unroll
            for (int i = 0; i < AI; i++) {
                int r0 = (wave * AI + i) * 8;
                const unsigned short* g = Az + (size_t)(bm + r0 + sub) * K + k0 + cpr * 8;
                __builtin_amdgcn_global_load_lds((GVoid*)g, (LVoid*)&As[r0 * 64], 16, 0, 0);
            }
#pragma unroll
            for (int i = 0; i < BI; i++) {
                int r0 = (wave * BI + i) * 8;
                const unsigned short* g = Wz + (size_t)(bn + r0 + sub) * K + k0 + cpr * 8;
                __builtin_amdgcn_global_load_lds((GVoid*)g, (LVoid*)&Bs[r0 * 64], 16, 0, 0);
            }
            __syncthreads();

#pragma unroll
            for (int h = 0; h < 2; h++) {
                bf16x8 af[RM], bf[RN];
#pragma unroll
                for (int i = 0; i < RM; i++) {
                    int r = wm * WTM + i * 16 + l16;
                    int ch = (h * 4 + quad) ^ (r & 7);
                    af[i] = *(const bf16x8*)&As[r * 64 + ch * 8];
                }
#pragma unroll
                for (int j = 0; j < RN; j++) {
                    int r = wn * WTN + j * 16 + l16;
                    int ch = (h * 4 + quad) ^ (r & 7);
                    bf[j] = *(const bf16x8*)&Bs[r * 64 + ch * 8];
                }
#pragma unroll
                for (int i = 0; i < RM; i++)
#pragma unroll
                    for (int j = 0; j < RN; j++)
                        acc[i][j] = __builtin_amdgcn_mfma_f32_16x16x32_bf16(af[i], bf[j], acc[i][j], 0, 0, 0);
            }
        }

#pragma unroll
        for (int i = 0; i < RM; i++) {
#pragma unroll
            for (int j = 0; j < RN; j++) {
                int c = bn + wn * WTN + j * 16 + l16;
                float bv = BIAS_ ? bias[c] : 0.f;
#pragma unroll
                for (int reg = 0; reg < 4; reg++) {
                    int r = bm + wm * WTM + i * 16 + quad * 4 + reg;
                    if (r < M) {
                        float v = acc[i][j][reg] + bv;
                        if (GELU_) v = gelu_exact(v);
                        if (FLAGS_) v *= rowflag[r >> 5];
                        if (OBF_)
                            ((unsigned short*)Cv)[(size_t)z * sC + (size_t)r * N + c] = f2bf(v);
                        else
                            ((float*)Cv)[(size_t)z * sC + (size_t)r * N + c] = v;
                    }
                }
            }
        }
    }
}

// ---- prep unit (one 256-thread block-unit of preprocessing) ----
__device__ __forceinline__ void prep_unit(const AllArgs& a, int bx, unsigned char* SM) {
    int tid = threadIdx.x;
    if (bx < a.nb_cvt) {                       // S0: f32->bf16 conversions
        int i = bx * 256 + tid;
        if (i < a.total4) {
            int k = 0;
#pragma unroll
            for (int j = 0; j < 8; j++) if (i >= a.cum4[j + 1]) k = j + 1;
            int o = i - a.cum4[k];
            float4 v = ((const float4*)a.csrc[k])[o];
            ushort4 u;
            u.x = f2bf(v.x); u.y = f2bf(v.y); u.z = f2bf(v.z); u.w = f2bf(v.w);
            ((ushort4*)a.cdst[k])[o] = u;
        }
        return;
    }
    bx -= a.nb_cvt;
    if (bx < 512) {                            // S1: vw transpose+convert
        float* tile = (float*)SM;              // [32][33]
        int l = bx >> 8, t16 = bx & 255;
        int j0 = (t16 >> 4) * 32, k0 = (t16 & 15) * 32;
        int tx = tid & 31, ty = tid >> 5;
        const float* src = a.ly_vw + (size_t)l * 512 * 512;
        for (int r = ty; r < 32; r += 8)
            tile[r * 33 + tx] = src[(size_t)(j0 + r) * 512 + k0 + tx];
        __syncthreads();
        unsigned short* dst = a.vwT + (size_t)l * 512 * 512;
        for (int r = ty; r < 32; r += 8)
            dst[(size_t)(k0 + r) * 512 + j0 + tx] = f2bf(tile[tx * 33 + r]);
        return;
    }
    bx -= 512;
    if (bx < 256) {                            // S2: bfuse wave-dots
        int wid = bx * 4 + (tid >> 6);
        int z = wid >> 9, n = wid & 511, lane = tid & 63;
        const float* owr = a.ly_ow + (size_t)z * 512 * 512 + (size_t)n * 512;
        const float* vbr = a.ly_vb + (size_t)z * 512;
        float s = 0.f;
#pragma unroll
        for (int j = 0; j < 8; j++) s += owr[lane + 64 * j] * vbr[lane + 64 * j];
#pragma unroll
        for (int off = 32; off; off >>= 1) s += __shfl_xor(s, off, 64);
        if (lane == 0) a.bfuse[z * 512 + n] = s + a.ly_ob[z * 512 + n];
        return;
    }
    bx -= 256;
    if (bx < 1) {                              // S3: kvb + flags
        float* red = (float*)SM;
        for (int n = tid; n < 512; n += 256) {
            a.kvb[n] = a.t_kb[n];
            a.kvb[n + 512] = a.t_vb[n];
        }
        for (int b = 0; b < B_; b++) {
            float s = a.edge_mask[b * E_ + tid];
#pragma unroll
            for (int off = 32; off; off >>= 1) s += __shfl_xor(s, off, 64);
            if ((tid & 63) == 0) red[tid >> 6] = s;
            __syncthreads();
            if (tid == 0)
                a.flags[b] = (red[0] + red[1] + red[2] + red[3] == 0.f) ? 0.f : 1.f;
            __syncthreads();
        }
        return;
    }
    bx -= 1;
    {                                          // S4: q-proj wave-dots
        int wid = bx * 4 + (tid >> 6);
        int m = wid >> 9, n = wid & 511, lane = tid & 63;
        const float* ar = a.mem_q + (size_t)m * 512;
        const float* br = a.t_qw + (size_t)n * 512;
        float s = 0.f;
#pragma unroll
        for (int j = 0; j < 8; j++) s += ar[lane + 64 * j] * br[lane + 64 * j];
#pragma unroll
        for (int off = 32; off; off >>= 1) s += __shfl_xor(s, off, 64);
        if (lane == 0) a.qbuf[(size_t)m * 512 + n] = s + a.t_qb[n];
    }
}

// ---- cosine top-k + aggregate unit (one edge) ----
__device__ __forceinline__ void topk_unit(const AllArgs& a, int be, unsigned char* SM) {
    int tid = threadIdx.x;
    float* ev = (float*)SM;                    // 512 f
    float* sims = (float*)(SM + 2048);         // 32 f
    int* nid_s = (int*)(SM + 2176);            // 32 i
    int* sel = (int*)(SM + 2304);              // 8 i

    int eid = a.eids[be];
    const float* ep = a.proj + (size_t)eid * D_;
    float e0 = ep[tid], e1 = ep[tid + 256];
    ev[tid] = e0; ev[tid + 256] = e1;
    a.states[(size_t)be * D_ + tid] = e0;
    a.states[(size_t)be * D_ + tid + 256] = e1;
    if (tid < 32) nid_s[tid] = a.nids[be * N_ + tid];
    __syncthreads();

    int wid = tid >> 6, lane = tid & 63;
    float se = 0.f;
#pragma unroll
    for (int j = 0; j < 8; j++) { float v = ev[lane + 64 * j]; se += v * v; }
#pragma unroll
    for (int off = 32; off; off >>= 1) se += __shfl_xor(se, off, 64);
    float en = fmaxf(sqrtf(se), 1e-12f);

    for (int n = wid; n < N_; n += 4) {
        int nid = nid_s[n];
        const float* np = a.proj + (size_t)nid * D_;
        float s = 0.f, s2 = 0.f;
#pragma unroll
        for (int j = 0; j < 8; j++) {
            float v = np[lane + 64 * j];
            s += v * ev[lane + 64 * j];
            s2 += v * v;
        }
#pragma unroll
        for (int off = 32; off; off >>= 1) {
            s += __shfl_xor(s, off, 64);
            s2 += __shfl_xor(s2, off, 64);
        }
        if (lane == 0) sims[n] = s / (fmaxf(sqrtf(s2), 1e-12f) * en);
    }
    __syncthreads();

    if (tid == 0) {
        unsigned used = 0;
        for (int k = 0; k < K_; k++) {
            float best = -3.402823466e38f; int bi = 0;
            for (int n = 0; n < N_; n++)
                if (!((used >> n) & 1u) && sims[n] > best) { best = sims[n]; bi = n; }
            used |= 1u << bi;
            sel[k] = nid_s[bi];
        }
    }
    __syncthreads();

    float a0 = 0.f, a1 = 0.f;
#pragma unroll
    for (int k = 0; k < K_; k++) {
        const float* sp = a.proj + (size_t)sel[k] * D_;
        a0 += sp[tid]; a1 += sp[tid + 256];
    }
    a.agg_bf[(size_t)be * D_ + tid] = f2bf(a0 * 0.125f);
    a.agg_bf[(size_t)be * D_ + tid + 256] = f2bf(a1 * 0.125f);
}

// ---- residual + layernorm rows (grid-stride) ----
__device__ __forceinline__ void add_ln_rows(const float* x, const float* y, int ystride,
                                            const float* g, const float* bb,
                                            const float* mask, float* out,
                                            unsigned short* out_bf, unsigned char* SM) {
    int tid = threadIdx.x;
    float* red = (float*)SM;
    for (int t = blockIdx.x; t < B_ * E_; t += gridDim.x) {
        const float* xr = x + (size_t)t * D_;
        const float* yr = y + (size_t)t * ystride;
        float x0 = xr[tid] + yr[tid];
        float x1 = xr[tid + 256] + yr[tid + 256];
        float s = x0 + x1;
#pragma unroll
        for (int off = 32; off; off >>= 1) s += __shfl_xor(s, off, 64);
        int wid = tid >> 6;
        if ((tid & 63) == 0) red[wid] = s;
        __syncthreads();
        float mean = (red[0] + red[1] + red[2] + red[3]) * (1.f / 512.f);
        float d0 = x0 - mean, d1 = x1 - mean;
        float v = d0 * d0 + d1 * d1;
#pragma unroll
        for (int off = 32; off; off >>= 1) v += __shfl_xor(v, off, 64);
        if ((tid & 63) == 0) red[4 + wid] = v;
        __syncthreads();
        float var = (red[4] + red[5] + red[6] + red[7]) * (1.f / 512.f);
        float rs = rsqrtf(var + 1e-5f);
        float mv = mask ? mask[t] : 1.f;
        float o0 = (d0 * rs * g[tid] + bb[tid]) * mv;
        float o1 = (d1 * rs * g[tid + 256] + bb[tid + 256]) * mv;
        out[(size_t)t * D_ + tid] = o0;
        out[(size_t)t * D_ + tid + 256] = o1;
        out_bf[(size_t)t * D_ + tid] = f2bf(o0);
        out_bf[(size_t)t * D_ + tid + 256] = f2bf(o1);
        __syncthreads();
    }
}

// ---- cross-attention units (one (b,m,h) each, grid-stride) ----
__device__ __forceinline__ void mem_attn_units(const AllArgs& a, unsigned char* SM) {
    int tid = threadIdx.x;
    float* qh = (float*)SM;                    // 64 f
    float* sc = (float*)(SM + 256);            // 256 f
    float* red = (float*)(SM + 1280);          // 8 f
    float* oacc = (float*)(SM + 1344);         // 256 f
    for (int idx = blockIdx.x; idx < B_ * M_ * H_; idx += gridDim.x) {
        __syncthreads();
        int b = idx & 7;
        int h = (idx >> 3) & 7;
        int m = idx >> 6;
        float mk = a.edge_mask[b * E_ + tid];
        if (tid < 64) qh[tid] = a.qbuf[m * D_ + h * DH_ + tid];
        __syncthreads();
        const float* kr = a.kvbuf + ((size_t)(b * E_ + tid)) * 1024 + h * DH_;
        float s = 0.f;
#pragma unroll
        for (int d = 0; d < DH_; d += 4) {
            float4 k4 = *(const float4*)(kr + d);
            s += k4.x * qh[d] + k4.y * qh[d + 1] + k4.z * qh[d + 2] + k4.w * qh[d + 3];
        }
        s *= 0.125f;
        if (mk == 0.f) s = -3.402823466e38f;
        float mx = s;
#pragma unroll
        for (int off = 32; off; off >>= 1) mx = fmaxf(mx, __shfl_xor(mx, off, 64));
        if ((tid & 63) == 0) red[tid >> 6] = mx;
        __syncthreads();
        mx = fmaxf(fmaxf(red[0], red[1]), fmaxf(red[2], red[3]));
        float p = expf(s - mx);
        float sum = p;
#pragma unroll
        for (int off = 32; off; off >>= 1) sum += __shfl_xor(sum, off, 64);
        if ((tid & 63) == 0) red[4 + (tid >> 6)] = sum;
        __syncthreads();
        sum = red[4] + red[5] + red[6] + red[7];
        sc[tid] = p / sum;
        __syncthreads();
        int d = tid & 63, part = tid >> 6;
        const float* vcol = a.kvbuf + ((size_t)(b * E_ + part * 64)) * 1024 + 512 + h * DH_ + d;
        float acc = 0.f;
#pragma unroll 8
        for (int e = 0; e < 64; e++) acc += sc[part * 64 + e] * vcol[(size_t)e * 1024];
        oacc[part * 64 + d] = acc;
        __syncthreads();
        if (part == 0)
            a.membf[((size_t)(b * M_ + m)) * D_ + h * DH_ + d] =
                f2bf(oacc[d] + oacc[64 + d] + oacc[128 + d] + oacc[192 + d]);
    }
}

__device__ __forceinline__ void run_stage(const AllArgs& a, int s, unsigned char* SM) {
    switch (s) {
    case 0:
        for (int u = blockIdx.x; u < a.nb_prep; u += gridDim.x) {
            __syncthreads();
            prep_unit(a, u, SM);
        }
        break;
    case 1:   // proj = rel_emb @ rp_w^T + rp_b  (f32 out)
        gemm_stage<32, 64, 0, 0, 1, 0>(a.rel_bf, a.rpw_bf, a.rp_b, a.proj,
                                       R_, D_, RD_, nullptr, 1, 0, 0, 0, SM);
        break;
    case 2:   // topk units + Wfuse = ow @ vw^T (z-batched)
        for (int u = blockIdx.x; u < B_ * E_; u += gridDim.x) {
            __syncthreads();
            topk_unit(a, u, SM);
        }
        gemm_stage<32, 64, 0, 1, 0, 0>(a.ow_bf, a.vwT, nullptr, a.wfuse,
                                       D_, D_, D_, nullptr, 2,
                                       (size_t)D_ * D_, (size_t)D_ * D_, (size_t)D_ * D_, SM);
        break;
    case 3:   // attnall = agg @ Wfuse^T + bfuse  [2048,1024]
        gemm_stage<64, 64, 0, 0, 1, 0>(a.agg_bf, a.wfuse, a.bfuse, a.attnall,
                                       B_ * E_, 2 * D_, D_, nullptr, 1, 0, 0, 0, SM);
        break;
    case 4: case 8: {   // LN1
        int l = (s - 4) / 4;
        add_ln_rows(a.states, a.attnall + (size_t)l * D_, 2 * D_,
                    a.n1g + l * D_, a.n1b + l * D_, nullptr,
                    a.states, a.states_bf, SM);
        break;
    }
    case 5: case 9: {   // ff1 (+GELU)
        int l = (s - 4) / 4;
        gemm_stage<64, 64, 1, 1, 1, 0>(a.states_bf, a.w1 + (size_t)l * 4 * D_ * D_,
                                       a.b1 + l * 4 * D_, a.ff1,
                                       B_ * E_, 4 * D_, D_, nullptr, 1, 0, 0, 0, SM);
        break;
    }
    case 6: case 10: {  // ff2
        int l = (s - 4) / 4;
        gemm_stage<32, 64, 0, 0, 1, 0>(a.ff1, a.w2 + (size_t)l * 4 * D_ * D_,
                                       a.b2 + l * D_, a.tmpB,
                                       B_ * E_, D_, 4 * D_, nullptr, 1, 0, 0, 0, SM);
        break;
    }
    case 7: case 11: {  // LN2 (* edge_mask)
        int l = (s - 4) / 4;
        add_ln_rows(a.states, a.tmpB, D_,
                    a.n2g + l * D_, a.n2b + l * D_, a.edge_mask,
                    a.states, a.states_bf, SM);
        break;
    }
    case 12:  // kv projection [2048,1024]
        gemm_stage<64, 64, 0, 0, 1, 0>(a.states_bf, a.kvw, a.kvb, a.kvbuf,
                                       B_ * E_, 2 * D_, D_, nullptr, 1, 0, 0, 0, SM);
        break;
    case 13:  // memory cross-attention
        mem_attn_units(a, SM);
        break;
    case 14:  // t_ow projection + no-edge zeroing via flags
        gemm_stage<32, 64, 0, 1, 1, 1>(a.membf, a.toww, a.t_ob, a.mem2,
                                       B_ * M_, D_, D_, a.flags, 1, 0, 0, 0, SM);
        break;
    case 15:  // final LLM projection (f32 out)
        gemm_stage<32, 64, 0, 0, 1, 0>(a.mem2, a.pw, a.proj_b, a.outp,
                                       B_ * M_, HL_, D_, nullptr, 1, 0, 0, 0, SM);
        break;
    }
}

__global__ __launch_bounds__(256, 2) void fused_all(AllArgs a, int s0, int s1) {
    __shared__ __align__(16) unsigned char SM[16896];
    cg::grid_group grid = cg::this_grid();
    for (int s = s0; s < s1; s++) {
        if (s > s0) grid.sync();
        run_stage(a, s, SM);
    }
}

extern "C" void kernel_launch(void* const* d_in, const int* in_sizes, int n_in,
                              void* d_out, int out_size, void* d_ws, size_t ws_size,
                              hipStream_t stream) {
    const int*   edge_rel_ids     = (const int*)d_in[0];
    const int*   neighbor_rel_ids = (const int*)d_in[1];
    const float* edge_mask        = (const float*)d_in[2];
    const float* rel_emb          = (const float*)d_in[3];
    const float* rp_w             = (const float*)d_in[4];
    const float* rp_b             = (const float*)d_in[5];
    const float* ly_vw            = (const float*)d_in[6];
    const float* ly_vb            = (const float*)d_in[7];
    const float* ly_ow            = (const float*)d_in[8];
    const float* ly_ob            = (const float*)d_in[9];
    const float* ly_n1g           = (const float*)d_in[10];
    const float* ly_n1b           = (const float*)d_in[11];
    const float* ly_n2g           = (const float*)d_in[12];
    const float* ly_n2b           = (const float*)d_in[13];
    const float* ly_w1            = (const float*)d_in[14];
    const float* ly_b1            = (const float*)d_in[15];
    const float* ly_w2            = (const float*)d_in[16];
    const float* ly_b2            = (const float*)d_in[17];
    const float* mem_q            = (const float*)d_in[18];
    const float* t_qw             = (const float*)d_in[19];
    const float* t_qb             = (const float*)d_in[20];
    const float* t_kw             = (const float*)d_in[21];
    const float* t_kb             = (const float*)d_in[22];
    const float* t_vw             = (const float*)d_in[23];
    const float* t_vb             = (const float*)d_in[24];
    const float* t_ow             = (const float*)d_in[25];
    const float* t_ob             = (const float*)d_in[26];
    const float* proj_w           = (const float*)d_in[27];
    const float* proj_b           = (const float*)d_in[28];
    (void)ws_size; (void)in_sizes; (void)n_in; (void)out_size;

    char* ws = (char*)d_ws;
    size_t off = 0;
    auto allocf = [&](size_t n) { float* p = (float*)(ws + off); off += ((n * 4 + 255) & ~(size_t)255); return p; };
    auto allocb = [&](size_t n) { unsigned short* p = (unsigned short*)(ws + off); off += ((n * 2 + 255) & ~(size_t)255); return p; };

    const int T = B_ * E_;

    float* proj    = allocf((size_t)R_ * D_);
    float* states  = allocf((size_t)T * D_);
    float* tmpB    = allocf((size_t)T * D_);
    float* attnall = allocf((size_t)T * 2 * D_);
    float* qbuf    = allocf((size_t)M_ * D_);
    float* bfuse   = allocf(2 * D_);
    float* kvb     = allocf(2 * D_);
    float* flags   = allocf(B_);
    float* kvbuf   = attnall;   // alias: attnall dead after layer stack

    unsigned short* rel_bf    = allocb((size_t)2048 * RD_);   // padded rows
    unsigned short* rpw_bf    = allocb((size_t)D_ * RD_);
    unsigned short* agg_bf    = allocb((size_t)T * D_);
    unsigned short* states_bf = allocb((size_t)T * D_);
    unsigned short* ff1_bf    = allocb((size_t)T * 4 * D_);
    unsigned short* vwT_bf    = allocb((size_t)L_ * D_ * D_);
    unsigned short* ow_bf     = allocb((size_t)L_ * D_ * D_);
    unsigned short* wfuse_bf  = allocb((size_t)L_ * D_ * D_);
    unsigned short* w1_bf     = allocb((size_t)L_ * 4 * D_ * D_);
    unsigned short* w2_bf     = allocb((size_t)L_ * 4 * D_ * D_);
    unsigned short* kvw_bf    = allocb((size_t)2 * D_ * D_);
    unsigned short* tow_bf    = allocb((size_t)D_ * D_);
    unsigned short* pw_bf     = allocb((size_t)HL_ * D_);
    unsigned short* memb_bf   = allocb((size_t)B_ * M_ * D_);
    unsigned short* mem2_bf   = allocb((size_t)B_ * M_ * D_);

    AllArgs a;
    int sizes[9] = { R_ * RD_, D_ * RD_, L_ * D_ * D_, L_ * 4 * D_ * D_,
                     L_ * 4 * D_ * D_, D_ * D_, D_ * D_, D_ * D_, HL_ * D_ };
    const float* srcs[9] = { rel_emb, rp_w, ly_ow, ly_w1, ly_w2, t_kw, t_vw, t_ow, proj_w };
    unsigned short* dsts[9] = { rel_bf, rpw_bf, ow_bf, w1_bf, w2_bf,
                                kvw_bf, kvw_bf + (size_t)D_ * D_, tow_bf, pw_bf };
    int cum = 0;
    for (int i = 0; i < 9; i++) {
        a.csrc[i] = srcs[i]; a.cdst[i] = dsts[i];
        a.cum4[i] = cum; cum += sizes[i] / 4;
    }
    a.cum4[9] = cum;
    a.total4 = cum;
    a.nb_cvt = (cum + 255) / 256;
    a.nb_prep = a.nb_cvt + 512 + 256 + 1 + 4096;
    a.ly_vw = ly_vw; a.vwT = vwT_bf;
    a.ly_ow = ly_ow; a.ly_vb = ly_vb; a.ly_ob = ly_ob; a.bfuse = bfuse;
    a.t_kb = t_kb; a.t_vb = t_vb; a.kvb = kvb;
    a.edge_mask = edge_mask; a.flags = flags;
    a.mem_q = mem_q; a.t_qw = t_qw; a.t_qb = t_qb; a.qbuf = qbuf;
    a.eids = edge_rel_ids; a.nids = neighbor_rel_ids;
    a.rel_bf = rel_bf; a.rpw_bf = rpw_bf; a.rp_b = rp_b; a.proj = proj;
    a.agg_bf = agg_bf; a.states = states; a.states_bf = states_bf;
    a.ow_bf = ow_bf; a.wfuse = wfuse_bf;
    a.attnall = attnall;
    a.n1g = ly_n1g; a.n1b = ly_n1b; a.n2g = ly_n2g; a.n2b = ly_n2b;
    a.w1 = w1_bf; a.b1 = ly_b1; a.w2 = w2_bf; a.b2 = ly_b2;
    a.ff1 = ff1_bf; a.tmpB = tmpB;
    a.kvw = kvw_bf; a.kvbuf = kvbuf;
    a.membf = memb_bf; a.toww = tow_bf; a.t_ob = t_ob; a.mem2 = mem2_bf;
    a.pw = pw_bf; a.proj_b = proj_b; a.outp = (float*)d_out;

    // One cooperative launch: 512 blocks (2/CU co-resident), 16 stages, 15 grid syncs.
    int s0 = 0, s1 = 16;
    void* kargs[] = { (void*)&a, (void*)&s0, (void*)&s1 };
    hipError_t err = hipLaunchCooperativeKernel((void*)fused_all, dim3(512), dim3(256),
                                                kargs, 0, stream);
    if (err != hipSuccess) {
        // Fallback: per-stage launches (no grid.sync needed) — R8-equivalent.
        for (int s = 0; s < 16; s++)
            fused_all<<<512, 256, 0, stream>>>(a, s, s + 1);
    }
}

// Round 10
// 407.944 us; speedup vs baseline: 3.0257x; 3.0257x over previous
//
#include <hip/hip_runtime.h>
#include <hip/hip_bf16.h>
#include <math.h>

#define B_   8
#define E_   256
#define N_   32
#define D_   512
#define RD_  768
#define R_   2000
#define L_   2
#define K_   8
#define M_   32
#define H_   8
#define DH_  64
#define HL_  4096

typedef float f32x4 __attribute__((ext_vector_type(4)));
typedef __bf16 bf16x8 __attribute__((ext_vector_type(8)));
typedef const __attribute__((address_space(1))) void GVoid;
typedef __attribute__((address_space(3))) void LVoid;

__device__ __forceinline__ float gelu_exact(float x) {
    return 0.5f * x * (1.0f + erff(x * 0.70710678118654752f));
}
__device__ __forceinline__ unsigned short f2bf(float x) {
    return __hip_bfloat16_raw(__float2bfloat16(x)).x;
}

// ---------------------------------------------------------------------------
// Plain bf16 MFMA GEMM (m97-style): C[M,N] = A @ W^T [+bias]. BK=64,
// global_load_lds width=16, XOR chunk-swizzle. TM in {32,64}, TN=64.
// A rows allocated to ceil(M/TM)*TM; store guarded r<M.
// ---------------------------------------------------------------------------
template <int TM, int TN, int ACT_GELU, int OUT_BF16, int HAS_BIAS, int FLAGS>
__global__ __launch_bounds__(256) void gemm_mfma(const unsigned short* __restrict__ A,
                                                 const unsigned short* __restrict__ W,
                                                 const float* __restrict__ bias,
                                                 void* __restrict__ Cv,
                                                 int M, int N, int K,
                                                 const float* __restrict__ rowflag) {
    constexpr int WTM = TM / 2, WTN = TN / 2;
    constexpr int RM = WTM / 16, RN = WTN / 16;
    constexpr int AI = TM / 32, BI = TN / 32;
    __shared__ __align__(16) unsigned short As[TM * 64];
    __shared__ __align__(16) unsigned short Bs[TN * 64];

    const int tid = threadIdx.x;
    const int wave = tid >> 6, lane = tid & 63;
    const int quad = lane >> 4, l16 = lane & 15;
    const int wm = wave >> 1, wn = wave & 1;
    const int bm = blockIdx.y * TM, bn = blockIdx.x * TN;
    const int sub = lane >> 3;
    const int cpr = (lane & 7) ^ sub;

    f32x4 acc[RM][RN];
#pragma unroll
    for (int i = 0; i < RM; i++)
#pragma unroll
        for (int j = 0; j < RN; j++) acc[i][j] = (f32x4){0.f, 0.f, 0.f, 0.f};

    for (int k0 = 0; k0 < K; k0 += 64) {
        __syncthreads();
#pragma unroll
        for (int i = 0; i < AI; i++) {
            int r0 = (wave * AI + i) * 8;
            const unsigned short* g = A + (size_t)(bm + r0 + sub) * K + k0 + cpr * 8;
            __builtin_amdgcn_global_load_lds((GVoid*)g, (LVoid*)&As[r0 * 64], 16, 0, 0);
        }
#pragma unroll
        for (int i = 0; i < BI; i++) {
            int r0 = (wave * BI + i) * 8;
            const unsigned short* g = W + (size_t)(bn + r0 + sub) * K + k0 + cpr * 8;
            __builtin_amdgcn_global_load_lds((GVoid*)g, (LVoid*)&Bs[r0 * 64], 16, 0, 0);
        }
        __syncthreads();
#pragma unroll
        for (int h = 0; h < 2; h++) {
            bf16x8 af[RM], bf[RN];
#pragma unroll
            for (int i = 0; i < RM; i++) {
                int r = wm * WTM + i * 16 + l16;
                int ch = (h * 4 + quad) ^ (r & 7);
                af[i] = *(const bf16x8*)&As[r * 64 + ch * 8];
            }
#pragma unroll
            for (int j = 0; j < RN; j++) {
                int r = wn * WTN + j * 16 + l16;
                int ch = (h * 4 + quad) ^ (r & 7);
                bf[j] = *(const bf16x8*)&Bs[r * 64 + ch * 8];
            }
#pragma unroll
            for (int i = 0; i < RM; i++)
#pragma unroll
                for (int j = 0; j < RN; j++)
                    acc[i][j] = __builtin_amdgcn_mfma_f32_16x16x32_bf16(af[i], bf[j], acc[i][j], 0, 0, 0);
        }
    }

#pragma unroll
    for (int i = 0; i < RM; i++) {
#pragma unroll
        for (int j = 0; j < RN; j++) {
            int c = bn + wn * WTN + j * 16 + l16;
            float bv = HAS_BIAS ? bias[c] : 0.f;
#pragma unroll
            for (int reg = 0; reg < 4; reg++) {
                int r = bm + wm * WTM + i * 16 + quad * 4 + reg;
                if (r < M) {
                    float v = acc[i][j][reg] + bv;
                    if (ACT_GELU) v = gelu_exact(v);
                    if (FLAGS) v *= rowflag[r >> 5];
                    if (OUT_BF16)
                        ((unsigned short*)Cv)[(size_t)r * N + c] = f2bf(v);
                    else
                        ((float*)Cv)[(size_t)r * N + c] = v;
                }
            }
        }
    }
}

// ---------------------------------------------------------------------------
// Merged proj + wfuse GEMM dispatch (both TM=32/TN=64, N=512, independent).
// Tiles 0..503: proj = rel_emb_bf @ rp_w^T + rp_b (f32 out, M=2000 guard, K=768)
// Tiles 504..759: wfuse_z = ow_z @ vwT_z^T (bf16 out, K=512), z = 0,1
// ---------------------------------------------------------------------------
__global__ __launch_bounds__(256) void projwfuse_kernel(
        const unsigned short* __restrict__ rel_bf, const unsigned short* __restrict__ rpw_bf,
        const float* __restrict__ rp_b, float* __restrict__ proj,
        const unsigned short* __restrict__ ow_bf, const unsigned short* __restrict__ vwT_bf,
        unsigned short* __restrict__ wfuse) {
    __shared__ __align__(16) unsigned short As[32 * 64];
    __shared__ __align__(16) unsigned short Bs[64 * 64];

    const unsigned short *A, *W;
    const float* bias;
    int Mg, Kg, bm, bn, obf;
    void* C;
    int t = blockIdx.x;
    if (t < 504) {
        A = rel_bf; W = rpw_bf; bias = rp_b; Mg = R_; Kg = RD_;
        C = proj; obf = 0; bn = (t & 7) * 64; bm = (t >> 3) * 32;
    } else {
        int u = t - 504, z = u >> 7, uu = u & 127;
        A = ow_bf + (size_t)z * 262144; W = vwT_bf + (size_t)z * 262144;
        bias = nullptr; Mg = 512; Kg = 512;
        C = wfuse + (size_t)z * 262144; obf = 1; bn = (uu & 7) * 64; bm = (uu >> 3) * 32;
    }

    const int tid = threadIdx.x;
    const int wave = tid >> 6, lane = tid & 63;
    const int quad = lane >> 4, l16 = lane & 15;
    const int wm = wave >> 1, wn = wave & 1;
    const int sub = lane >> 3;
    const int cpr = (lane & 7) ^ sub;

    f32x4 acc[1][2];
    acc[0][0] = (f32x4){0.f, 0.f, 0.f, 0.f};
    acc[0][1] = (f32x4){0.f, 0.f, 0.f, 0.f};

    for (int k0 = 0; k0 < Kg; k0 += 64) {
        __syncthreads();
        {   // A: TM=32 -> AI=1
            int r0 = wave * 8;
            const unsigned short* g = A + (size_t)(bm + r0 + sub) * Kg + k0 + cpr * 8;
            __builtin_amdgcn_global_load_lds((GVoid*)g, (LVoid*)&As[r0 * 64], 16, 0, 0);
        }
#pragma unroll
        for (int i = 0; i < 2; i++) {
            int r0 = (wave * 2 + i) * 8;
            const unsigned short* g = W + (size_t)(bn + r0 + sub) * Kg + k0 + cpr * 8;
            __builtin_amdgcn_global_load_lds((GVoid*)g, (LVoid*)&Bs[r0 * 64], 16, 0, 0);
        }
        __syncthreads();
#pragma unroll
        for (int h = 0; h < 2; h++) {
            bf16x8 af, bf[2];
            {
                int r = wm * 16 + l16;
                int ch = (h * 4 + quad) ^ (r & 7);
                af = *(const bf16x8*)&As[r * 64 + ch * 8];
            }
#pragma unroll
            for (int j = 0; j < 2; j++) {
                int r = wn * 32 + j * 16 + l16;
                int ch = (h * 4 + quad) ^ (r & 7);
                bf[j] = *(const bf16x8*)&Bs[r * 64 + ch * 8];
            }
#pragma unroll
            for (int j = 0; j < 2; j++)
                acc[0][j] = __builtin_amdgcn_mfma_f32_16x16x32_bf16(af, bf[j], acc[0][j], 0, 0, 0);
        }
    }

#pragma unroll
    for (int j = 0; j < 2; j++) {
        int c = bn + wn * 32 + j * 16 + l16;
        float bv = bias ? bias[c] : 0.f;
#pragma unroll
        for (int reg = 0; reg < 4; reg++) {
            int r = bm + wm * 16 + quad * 4 + reg;
            if (r < Mg) {
                float v = acc[0][j][reg] + bv;
                if (obf)
                    ((unsigned short*)C)[(size_t)r * 512 + c] = f2bf(v);
                else
                    ((float*)C)[(size_t)r * 512 + c] = v;
            }
        }
    }
}

// ---------------------------------------------------------------------------
// LN-fused GEMM: A rows are LayerNorm outputs computed in-block.
// LNMODE 1: A[r] = LN(x[r]+y[r])*g1+b1 (*mask1[r])
// LNMODE 2: t = (LN(x[r]+y[r])*g1+b1)*mask1[r]; A[r] = LN(t+y2[r])*g2+b2
// TM=64, TN=64, K%64==0, rows = 2048 (no M guard). bn==0 blocks write the f32
// A rows to states_out (if non-null) for the next stage's residual.
// ---------------------------------------------------------------------------
template <int ACT_GELU, int OUT_BF16, int LNMODE>
__global__ __launch_bounds__(256) void gemm_ln(
        const float* __restrict__ x, const float* __restrict__ y, int ystride,
        const float* __restrict__ g1, const float* __restrict__ b1,
        const float* __restrict__ mask1,
        const float* __restrict__ y2, int y2stride,
        const float* __restrict__ g2, const float* __restrict__ b2,
        const unsigned short* __restrict__ W, const float* __restrict__ bias,
        void* __restrict__ Cv, float* __restrict__ states_out, int N, int K) {
    __shared__ __align__(16) unsigned short As[64 * 64];
    __shared__ __align__(16) unsigned short Bs[64 * 64];
    __shared__ float stats[5 * 64];
    float* meanA = stats;
    float* rsA = stats + 64;
    float* mvA = stats + 128;
    float* mean2A = stats + 192;
    float* rs2A = stats + 256;

    const int tid = threadIdx.x;
    const int wave = tid >> 6, lane = tid & 63;
    const int quad = lane >> 4, l16 = lane & 15;
    const int wm = wave >> 1, wn = wave & 1;
    const int bm = blockIdx.y * 64, bn = blockIdx.x * 64;
    const int sub = lane >> 3;
    const int cpr = (lane & 7) ^ sub;

    // ---- stats prologue: wave w handles rows i = pass*4 + w ----
    for (int pass = 0; pass < 16; pass++) {
        int i = pass * 4 + wave;
        int r = bm + i;
        const float* xr = x + (size_t)r * D_;
        const float* yr = y + (size_t)r * ystride;
        float vreg[8];
        float s = 0.f;
#pragma unroll
        for (int j = 0; j < 8; j++) {
            float v = xr[lane + 64 * j] + yr[lane + 64 * j];
            vreg[j] = v; s += v;
        }
#pragma unroll
        for (int off = 32; off; off >>= 1) s += __shfl_xor(s, off, 64);
        float mean = s * (1.f / 512.f);
        float var = 0.f;
#pragma unroll
        for (int j = 0; j < 8; j++) { float d = vreg[j] - mean; var += d * d; }
#pragma unroll
        for (int off = 32; off; off >>= 1) var += __shfl_xor(var, off, 64);
        float rs = rsqrtf(var * (1.f / 512.f) + 1e-5f);
        float mv = mask1 ? mask1[r] : 1.f;
        if (LNMODE == 2) {
            const float* y2r = y2 + (size_t)r * y2stride;
            float treg[8];
            float s2 = 0.f;
#pragma unroll
            for (int j = 0; j < 8; j++) {
                int idx = lane + 64 * j;
                float tv = ((vreg[j] - mean) * rs * g1[idx] + b1[idx]) * mv + y2r[idx];
                treg[j] = tv; s2 += tv;
            }
#pragma unroll
            for (int off = 32; off; off >>= 1) s2 += __shfl_xor(s2, off, 64);
            float mean2 = s2 * (1.f / 512.f);
            float var2 = 0.f;
#pragma unroll
            for (int j = 0; j < 8; j++) { float d = treg[j] - mean2; var2 += d * d; }
#pragma unroll
            for (int off = 32; off; off >>= 1) var2 += __shfl_xor(var2, off, 64);
            float rs2 = rsqrtf(var2 * (1.f / 512.f) + 1e-5f);
            if (lane == 0) {
                meanA[i] = mean; rsA[i] = rs; mvA[i] = mv;
                mean2A[i] = mean2; rs2A[i] = rs2;
            }
        } else {
            if (lane == 0) { meanA[i] = mean; rsA[i] = rs; mvA[i] = mv; }
        }
    }

    f32x4 acc[2][2];
#pragma unroll
    for (int i = 0; i < 2; i++)
#pragma unroll
        for (int j = 0; j < 2; j++) acc[i][j] = (f32x4){0.f, 0.f, 0.f, 0.f};

    const bool wout = (states_out != nullptr) && (blockIdx.x == 0);

    for (int k0 = 0; k0 < K; k0 += 64) {
        __syncthreads();
        // B staging (async)
#pragma unroll
        for (int i = 0; i < 2; i++) {
            int r0 = (wave * 2 + i) * 8;
            const unsigned short* g = W + (size_t)(bn + r0 + sub) * K + k0 + cpr * 8;
            __builtin_amdgcn_global_load_lds((GVoid*)g, (LVoid*)&Bs[r0 * 64], 16, 0, 0);
        }
        // A staging: compute LN values, ds_write swizzled
#pragma unroll
        for (int rep = 0; rep < 2; rep++) {
            int linear = tid + rep * 256;
            int r = linear >> 3, c = linear & 7, slot = c ^ (r & 7);
            int rg = bm + r, kg = k0 + c * 8;
            const float* xr = x + (size_t)rg * D_ + kg;
            const float* yr = y + (size_t)rg * ystride + kg;
            float mean = meanA[r], rs = rsA[r], mv = mvA[r];
            float outv[8];
#pragma unroll
            for (int j = 0; j < 8; j++) {
                float v = ((xr[j] + yr[j]) - mean) * rs * g1[kg + j] + b1[kg + j];
                v *= mv;
                if (LNMODE == 2) {
                    v = (v + y2[(size_t)rg * y2stride + kg + j] - mean2A[r]) * rs2A[r]
                            * g2[kg + j] + b2[kg + j];
                }
                outv[j] = v;
            }
            if (wout) {
#pragma unroll
                for (int j = 0; j < 8; j++) states_out[(size_t)rg * D_ + kg + j] = outv[j];
            }
            uint4 pk;
            pk.x = (unsigned)f2bf(outv[0]) | ((unsigned)f2bf(outv[1]) << 16);
            pk.y = (unsigned)f2bf(outv[2]) | ((unsigned)f2bf(outv[3]) << 16);
            pk.z = (unsigned)f2bf(outv[4]) | ((unsigned)f2bf(outv[5]) << 16);
            pk.w = (unsigned)f2bf(outv[6]) | ((unsigned)f2bf(outv[7]) << 16);
            *(uint4*)&As[r * 64 + slot * 8] = pk;
        }
        __syncthreads();
#pragma unroll
        for (int h = 0; h < 2; h++) {
            bf16x8 af[2], bfv[2];
#pragma unroll
            for (int i = 0; i < 2; i++) {
                int r = wm * 32 + i * 16 + l16;
                int ch = (h * 4 + quad) ^ (r & 7);
                af[i] = *(const bf16x8*)&As[r * 64 + ch * 8];
            }
#pragma unroll
            for (int j = 0; j < 2; j++) {
                int r = wn * 32 + j * 16 + l16;
                int ch = (h * 4 + quad) ^ (r & 7);
                bfv[j] = *(const bf16x8*)&Bs[r * 64 + ch * 8];
            }
#pragma unroll
            for (int i = 0; i < 2; i++)
#pragma unroll
                for (int j = 0; j < 2; j++)
                    acc[i][j] = __builtin_amdgcn_mfma_f32_16x16x32_bf16(af[i], bfv[j], acc[i][j], 0, 0, 0);
        }
    }

#pragma unroll
    for (int i = 0; i < 2; i++) {
#pragma unroll
        for (int j = 0; j < 2; j++) {
            int c = bn + wn * 32 + j * 16 + l16;
            float bv = bias[c];
#pragma unroll
            for (int reg = 0; reg < 4; reg++) {
                int r = bm + wm * 32 + i * 16 + quad * 4 + reg;
                float v = acc[i][j][reg] + bv;
                if (ACT_GELU) v = gelu_exact(v);
                if (OUT_BF16)
                    ((unsigned short*)Cv)[(size_t)r * N + c] = f2bf(v);
                else
                    ((float*)Cv)[(size_t)r * N + c] = v;
            }
        }
    }
}

// ---------------------------------------------------------------------------
// prep_all: one launch for all input-only preprocessing (same as R8).
// ---------------------------------------------------------------------------
struct PrepArgs {
    const float* src[9];
    unsigned short* dst[9];
    int cum4[10];
    int nb_cvt, total4;
    const float* ly_vw; unsigned short* vwT;
    const float* ly_ow; const float* ly_vb; const float* ly_ob; float* bfuse;
    const float* t_kb; const float* t_vb; float* kvb;
    const float* edge_mask; float* flags;
    const float* mem_q; const float* t_qw; const float* t_qb; float* qbuf;
};

__global__ __launch_bounds__(256) void prep_all(PrepArgs a) {
    int bx = blockIdx.x, tid = threadIdx.x;
    if (bx < a.nb_cvt) {
        int i = bx * 256 + tid;
        if (i < a.total4) {
            int k = 0;
#pragma unroll
            for (int j = 0; j < 8; j++) if (i >= a.cum4[j + 1]) k = j + 1;
            int o = i - a.cum4[k];
            float4 v = ((const float4*)a.src[k])[o];
            ushort4 u;
            u.x = f2bf(v.x); u.y = f2bf(v.y); u.z = f2bf(v.z); u.w = f2bf(v.w);
            ((ushort4*)a.dst[k])[o] = u;
        }
        return;
    }
    bx -= a.nb_cvt;
    if (bx < 512) {                            // vw transpose+convert
        __shared__ float tile[32][33];
        int l = bx >> 8, t16 = bx & 255;
        int j0 = (t16 >> 4) * 32, k0 = (t16 & 15) * 32;
        int tx = tid & 31, ty = tid >> 5;
        const float* src = a.ly_vw + (size_t)l * 512 * 512;
        for (int r = ty; r < 32; r += 8)
            tile[r][tx] = src[(size_t)(j0 + r) * 512 + k0 + tx];
        __syncthreads();
        unsigned short* dst = a.vwT + (size_t)l * 512 * 512;
        for (int r = ty; r < 32; r += 8)
            dst[(size_t)(k0 + r) * 512 + j0 + tx] = f2bf(tile[tx][r]);
        return;
    }
    bx -= 512;
    if (bx < 256) {                            // bfuse wave-dots
        int wid = bx * 4 + (tid >> 6);
        int z = wid >> 9, n = wid & 511, lane = tid & 63;
        const float* owr = a.ly_ow + (size_t)z * 512 * 512 + (size_t)n * 512;
        const float* vbr = a.ly_vb + (size_t)z * 512;
        float s = 0.f;
#pragma unroll
        for (int j = 0; j < 8; j++) s += owr[lane + 64 * j] * vbr[lane + 64 * j];
#pragma unroll
        for (int off = 32; off; off >>= 1) s += __shfl_xor(s, off, 64);
        if (lane == 0) a.bfuse[z * 512 + n] = s + a.ly_ob[z * 512 + n];
        return;
    }
    bx -= 256;
    if (bx < 1) {                              // kvb + flags
        __shared__ float red[4];
        for (int n = tid; n < 512; n += 256) {
            a.kvb[n] = a.t_kb[n];
            a.kvb[n + 512] = a.t_vb[n];
        }
        for (int b = 0; b < B_; b++) {
            float s = a.edge_mask[b * E_ + tid];
#pragma unroll
            for (int off = 32; off; off >>= 1) s += __shfl_xor(s, off, 64);
            if ((tid & 63) == 0) red[tid >> 6] = s;
            __syncthreads();
            if (tid == 0)
                a.flags[b] = (red[0] + red[1] + red[2] + red[3] == 0.f) ? 0.f : 1.f;
            __syncthreads();
        }
        return;
    }
    bx -= 1;
    {                                          // q-proj wave-dots
        int wid = bx * 4 + (tid >> 6);
        int m = wid >> 9, n = wid & 511, lane = tid & 63;
        const float* ar = a.mem_q + (size_t)m * 512;
        const float* br = a.t_qw + (size_t)n * 512;
        float s = 0.f;
#pragma unroll
        for (int j = 0; j < 8; j++) s += ar[lane + 64 * j] * br[lane + 64 * j];
#pragma unroll
        for (int off = 32; off; off >>= 1) s += __shfl_xor(s, off, 64);
        if (lane == 0) a.qbuf[(size_t)m * 512 + n] = s + a.t_qb[n];
    }
}

// Per-edge cosine sims (norms inline) -> wave-parallel top-8 (strict >, lowest
// index on ties = lax.top_k) -> mean agg (bf16) + states init (f32).
__global__ void sim_topk_agg(const int* __restrict__ eids, const int* __restrict__ nids,
                             const float* __restrict__ proj,
                             unsigned short* __restrict__ agg_bf, float* __restrict__ states) {
    int be = blockIdx.x, tid = threadIdx.x;
    __shared__ float ev[512];
    __shared__ float sims[32];
    __shared__ int nid_s[32];
    __shared__ int sel[8];

    int eid = eids[be];
    const float* ep = proj + (size_t)eid * D_;
    float e0 = ep[tid], e1 = ep[tid + 256];
    ev[tid] = e0; ev[tid + 256] = e1;
    states[(size_t)be * D_ + tid] = e0;
    states[(size_t)be * D_ + tid + 256] = e1;
    if (tid < 32) nid_s[tid] = nids[be * N_ + tid];
    __syncthreads();

    int wid = tid >> 6, lane = tid & 63;
    float se = 0.f;
#pragma unroll
    for (int j = 0; j < 8; j++) { float v = ev[lane + 64 * j]; se += v * v; }
#pragma unroll
    for (int off = 32; off; off >>= 1) se += __shfl_xor(se, off, 64);
    float en = fmaxf(sqrtf(se), 1e-12f);

    for (int n = wid; n < N_; n += 4) {
        int nid = nid_s[n];
        const float* np = proj + (size_t)nid * D_;
        float s = 0.f, s2 = 0.f;
#pragma unroll
        for (int j = 0; j < 8; j++) {
            float v = np[lane + 64 * j];
            s += v * ev[lane + 64 * j];
            s2 += v * v;
        }
#pragma unroll
        for (int off = 32; off; off >>= 1) {
            s += __shfl_xor(s, off, 64);
            s2 += __shfl_xor(s2, off, 64);
        }
        if (lane == 0) sims[n] = s / (fmaxf(sqrtf(s2), 1e-12f) * en);
    }
    __syncthreads();

    if (tid < 64) {                            // wave-parallel top-8
        float v = (tid < 32) ? sims[tid] : -3.402823466e38f;
        int idx = tid;
        for (int k = 0; k < K_; k++) {
            float bv = v; int bi = idx;
#pragma unroll
            for (int off = 32; off; off >>= 1) {
                float ov = __shfl_xor(bv, off, 64);
                int oi = __shfl_xor(bi, off, 64);
                if (ov > bv || (ov == bv && oi < bi)) { bv = ov; bi = oi; }
            }
            if (tid == 0) sel[k] = nid_s[bi];
            if (idx == bi) v = -3.402823466e38f;
        }
    }
    __syncthreads();

    float a0 = 0.f, a1 = 0.f;
#pragma unroll
    for (int k = 0; k < K_; k++) {
        const float* sp = proj + (size_t)sel[k] * D_;
        a0 += sp[tid]; a1 += sp[tid + 256];
    }
    agg_bf[(size_t)be * D_ + tid] = f2bf(a0 * 0.125f);
    agg_bf[(size_t)be * D_ + tid + 256] = f2bf(a1 * 0.125f);
}

// Cross-attention over combined kv [T,1024]. grid = B_*M_*H_ (b in low bits).
__global__ void mem_attn(const float* __restrict__ qb, const float* __restrict__ kv,
                         const float* __restrict__ mask, unsigned short* __restrict__ memb) {
    int idx = blockIdx.x;
    int b = idx & 7;
    int h = (idx >> 3) & 7;
    int m = idx >> 6;
    int tid = threadIdx.x;
    __shared__ float qh[64];
    __shared__ float sc[256];
    __shared__ float red[8];
    __shared__ float oacc[4][64];

    float mk = mask[b * E_ + tid];
    if (tid < 64) qh[tid] = qb[m * D_ + h * DH_ + tid];
    __syncthreads();
    const float* kr = kv + ((size_t)(b * E_ + tid)) * 1024 + h * DH_;
    float s = 0.f;
#pragma unroll
    for (int d = 0; d < DH_; d += 4) {
        float4 k4 = *(const float4*)(kr + d);
        s += k4.x * qh[d] + k4.y * qh[d + 1] + k4.z * qh[d + 2] + k4.w * qh[d + 3];
    }
    s *= 0.125f;
    if (mk == 0.f) s = -3.402823466e38f;
    float mx = s;
#pragma unroll
    for (int off = 32; off; off >>= 1) mx = fmaxf(mx, __shfl_xor(mx, off, 64));
    if ((tid & 63) == 0) red[tid >> 6] = mx;
    __syncthreads();
    mx = fmaxf(fmaxf(red[0], red[1]), fmaxf(red[2], red[3]));
    float p = expf(s - mx);
    float sum = p;
#pragma unroll
    for (int off = 32; off; off >>= 1) sum += __shfl_xor(sum, off, 64);
    if ((tid & 63) == 0) red[4 + (tid >> 6)] = sum;
    __syncthreads();
    sum = red[4] + red[5] + red[6] + red[7];
    sc[tid] = p / sum;
    __syncthreads();
    int d = tid & 63, part = tid >> 6;
    const float* vcol = kv + ((size_t)(b * E_ + part * 64)) * 1024 + 512 + h * DH_ + d;
    float acc = 0.f;
#pragma unroll 8
    for (int e = 0; e < 64; e++) acc += sc[part * 64 + e] * vcol[(size_t)e * 1024];
    oacc[part][d] = acc;
    __syncthreads();
    if (part == 0)
        memb[((size_t)(b * M_ + m)) * D_ + h * DH_ + d] =
            f2bf(oacc[0][d] + oacc[1][d] + oacc[2][d] + oacc[3][d]);
}

extern "C" void kernel_launch(void* const* d_in, const int* in_sizes, int n_in,
                              void* d_out, int out_size, void* d_ws, size_t ws_size,
                              hipStream_t stream) {
    const int*   edge_rel_ids     = (const int*)d_in[0];
    const int*   neighbor_rel_ids = (const int*)d_in[1];
    const float* edge_mask        = (const float*)d_in[2];
    const float* rel_emb          = (const float*)d_in[3];
    const float* rp_w             = (const float*)d_in[4];
    const float* rp_b             = (const float*)d_in[5];
    const float* ly_vw            = (const float*)d_in[6];
    const float* ly_vb            = (const float*)d_in[7];
    const float* ly_ow            = (const float*)d_in[8];
    const float* ly_ob            = (const float*)d_in[9];
    const float* ly_n1g           = (const float*)d_in[10];
    const float* ly_n1b           = (const float*)d_in[11];
    const float* ly_n2g           = (const float*)d_in[12];
    const float* ly_n2b           = (const float*)d_in[13];
    const float* ly_w1            = (const float*)d_in[14];
    const float* ly_b1            = (const float*)d_in[15];
    const float* ly_w2            = (const float*)d_in[16];
    const float* ly_b2            = (const float*)d_in[17];
    const float* mem_q            = (const float*)d_in[18];
    const float* t_qw             = (const float*)d_in[19];
    const float* t_qb             = (const float*)d_in[20];
    const float* t_kw             = (const float*)d_in[21];
    const float* t_kb             = (const float*)d_in[22];
    const float* t_vw             = (const float*)d_in[23];
    const float* t_vb             = (const float*)d_in[24];
    const float* t_ow             = (const float*)d_in[25];
    const float* t_ob             = (const float*)d_in[26];
    const float* proj_w           = (const float*)d_in[27];
    const float* proj_b           = (const float*)d_in[28];
    float* out = (float*)d_out;
    (void)ws_size; (void)in_sizes; (void)n_in; (void)out_size;

    char* ws = (char*)d_ws;
    size_t off = 0;
    auto allocf = [&](size_t n) { float* p = (float*)(ws + off); off += ((n * 4 + 255) & ~(size_t)255); return p; };
    auto allocb = [&](size_t n) { unsigned short* p = (unsigned short*)(ws + off); off += ((n * 2 + 255) & ~(size_t)255); return p; };

    const int T = B_ * E_;

    float* proj    = allocf((size_t)R_ * D_);
    float* states  = allocf((size_t)T * D_);   // states0, later states3
    float* statesX = allocf((size_t)T * D_);   // states1 (post-LN1 l0)
    float* tmpB    = allocf((size_t)T * D_);
    float* attnall = allocf((size_t)T * 2 * D_);
    float* qbuf    = allocf((size_t)M_ * D_);
    float* bfuse   = allocf(2 * D_);
    float* kvb     = allocf(2 * D_);
    float* flags   = allocf(B_);
    float* kvbuf   = attnall;   // alias: attnall dead once ff1(l1) has consumed it

    unsigned short* rel_bf  = allocb((size_t)2048 * RD_);   // rows padded to 2048
    unsigned short* rpw_bf  = allocb((size_t)D_ * RD_);
    unsigned short* agg_bf  = allocb((size_t)T * D_);
    unsigned short* ff1_bf  = allocb((size_t)T * 4 * D_);
    unsigned short* vwT_bf  = allocb((size_t)L_ * D_ * D_);
    unsigned short* ow_bf   = allocb((size_t)L_ * D_ * D_);
    unsigned short* wfuse   = allocb((size_t)L_ * D_ * D_);
    unsigned short* w1_bf   = allocb((size_t)L_ * 4 * D_ * D_);
    unsigned short* w2_bf   = allocb((size_t)L_ * 4 * D_ * D_);
    unsigned short* kvw_bf  = allocb((size_t)2 * D_ * D_);
    unsigned short* tow_bf  = allocb((size_t)D_ * D_);
    unsigned short* pw_bf   = allocb((size_t)HL_ * D_);
    unsigned short* memb_bf = allocb((size_t)B_ * M_ * D_);
    unsigned short* mem2_bf = allocb((size_t)B_ * M_ * D_);

    // ---- 1. prep (conversions + transpose + bfuse/kvb/flags + q-proj) ----
    PrepArgs a;
    int sizes[9] = { R_ * RD_, D_ * RD_, L_ * D_ * D_, L_ * 4 * D_ * D_,
                     L_ * 4 * D_ * D_, D_ * D_, D_ * D_, D_ * D_, HL_ * D_ };
    const float* srcs[9] = { rel_emb, rp_w, ly_ow, ly_w1, ly_w2, t_kw, t_vw, t_ow, proj_w };
    unsigned short* dsts[9] = { rel_bf, rpw_bf, ow_bf, w1_bf, w2_bf,
                                kvw_bf, kvw_bf + (size_t)D_ * D_, tow_bf, pw_bf };
    int cum = 0;
    for (int i = 0; i < 9; i++) {
        a.src[i] = srcs[i]; a.dst[i] = dsts[i];
        a.cum4[i] = cum; cum += sizes[i] / 4;
    }
    a.cum4[9] = cum;
    a.total4 = cum;
    a.nb_cvt = (cum + 255) / 256;
    a.ly_vw = ly_vw; a.vwT = vwT_bf;
    a.ly_ow = ly_ow; a.ly_vb = ly_vb; a.ly_ob = ly_ob; a.bfuse = bfuse;
    a.t_kb = t_kb; a.t_vb = t_vb; a.kvb = kvb;
    a.edge_mask = edge_mask; a.flags = flags;
    a.mem_q = mem_q; a.t_qw = t_qw; a.t_qb = t_qb; a.qbuf = qbuf;
    int nblk = a.nb_cvt + 512 + 256 + 1 + 4096;
    prep_all<<<nblk, 256, 0, stream>>>(a);

    // ---- 2. proj + wfuse merged (760 tiles) ----
    projwfuse_kernel<<<760, 256, 0, stream>>>(rel_bf, rpw_bf, rp_b, proj,
                                              ow_bf, vwT_bf, wfuse);

    // ---- 3. sims + top-k + aggregate + states init ----
    sim_topk_agg<<<T, 256, 0, stream>>>(edge_rel_ids, neighbor_rel_ids, proj,
                                        agg_bf, states);

    // ---- 4. attn (both layers) = agg @ wfuse^T + bfuse  [2048,1024] ----
    gemm_mfma<64, 64, 0, 0, 1, 0><<<dim3(16, 32), 256, 0, stream>>>(
        agg_bf, wfuse, bfuse, attnall, T, 2 * D_, D_, nullptr);

    // ---- 5. ff1(l0) with fused LN1(l0); bn==0 writes states1 ----
    gemm_ln<1, 1, 1><<<dim3(32, 32), 256, 0, stream>>>(
        states, attnall, 2 * D_, ly_n1g, ly_n1b, nullptr,
        nullptr, 0, nullptr, nullptr,
        w1_bf, ly_b1, ff1_bf, statesX, 4 * D_, D_);
    // ---- 6. ff2(l0) ----
    gemm_mfma<32, 64, 0, 0, 1, 0><<<dim3(8, 64), 256, 0, stream>>>(
        ff1_bf, w2_bf, ly_b2, tmpB, T, D_, 4 * D_, nullptr);
    // ---- 7. ff1(l1) with fused LN2(l0)+LN1(l1); bn==0 writes states3 ----
    gemm_ln<1, 1, 2><<<dim3(32, 32), 256, 0, stream>>>(
        statesX, tmpB, D_, ly_n2g, ly_n2b, edge_mask,
        attnall + D_, 2 * D_, ly_n1g + D_, ly_n1b + D_,
        w1_bf + (size_t)4 * D_ * D_, ly_b1 + 4 * D_, ff1_bf, states, 4 * D_, D_);
    // ---- 8. ff2(l1) ----
    gemm_mfma<32, 64, 0, 0, 1, 0><<<dim3(8, 64), 256, 0, stream>>>(
        ff1_bf, w2_bf + (size_t)4 * D_ * D_, ly_b2 + D_, tmpB, T, D_, 4 * D_, nullptr);

    // ---- 9. kv projection with fused LN2(l1) (f32 out, [2048,1024]) ----
    gemm_ln<0, 0, 1><<<dim3(16, 32), 256, 0, stream>>>(
        states, tmpB, D_, ly_n2g + D_, ly_n2b + D_, edge_mask,
        nullptr, 0, nullptr, nullptr,
        kvw_bf, kvb, kvbuf, nullptr, 2 * D_, D_);

    // ---- 10. memory cross-attention ----
    mem_attn<<<B_ * M_ * H_, 256, 0, stream>>>(qbuf, kvbuf, edge_mask, memb_bf);

    // ---- 11. t_ow projection + no-edge zeroing via flags ----
    gemm_mfma<32, 64, 0, 1, 1, 1><<<dim3(8, 8), 256, 0, stream>>>(
        memb_bf, tow_bf, t_ob, mem2_bf, B_ * M_, D_, D_, flags);

    // ---- 12. final LLM projection ----
    gemm_mfma<32, 64, 0, 0, 1, 0><<<dim3(64, 8), 256, 0, stream>>>(
        mem2_bf, pw_bf, proj_b, out, B_ * M_, HL_, D_, nullptr);
}

// Round 11
// 309.202 us; speedup vs baseline: 3.9920x; 1.3193x over previous
//
#include <hip/hip_runtime.h>
#include <hip/hip_bf16.h>
#include <math.h>

#define B_   8
#define E_   256
#define N_   32
#define D_   512
#define RD_  768
#define R_   2000
#define L_   2
#define K_   8
#define M_   32
#define H_   8
#define DH_  64
#define HL_  4096

typedef float f32x4 __attribute__((ext_vector_type(4)));
typedef __bf16 bf16x8 __attribute__((ext_vector_type(8)));
typedef const __attribute__((address_space(1))) void GVoid;
typedef __attribute__((address_space(3))) void LVoid;

__device__ __forceinline__ float gelu_exact(float x) {
    return 0.5f * x * (1.0f + erff(x * 0.70710678118654752f));
}
__device__ __forceinline__ unsigned short f2bf(float x) {
    return __hip_bfloat16_raw(__float2bfloat16(x)).x;
}

// ---------------------------------------------------------------------------
// Plain bf16 MFMA GEMM (m97-style): C[M,N] = A @ W^T [+bias]. BK=64,
// global_load_lds width=16, XOR chunk-swizzle. TM in {32,64}, TN=64.
// A rows allocated to ceil(M/TM)*TM; store guarded r<M.
// ---------------------------------------------------------------------------
template <int TM, int TN, int ACT_GELU, int OUT_BF16, int HAS_BIAS, int FLAGS>
__global__ __launch_bounds__(256) void gemm_mfma(const unsigned short* __restrict__ A,
                                                 const unsigned short* __restrict__ W,
                                                 const float* __restrict__ bias,
                                                 void* __restrict__ Cv,
                                                 int M, int N, int K,
                                                 const float* __restrict__ rowflag) {
    constexpr int WTM = TM / 2, WTN = TN / 2;
    constexpr int RM = WTM / 16, RN = WTN / 16;
    constexpr int AI = TM / 32, BI = TN / 32;
    __shared__ __align__(16) unsigned short As[TM * 64];
    __shared__ __align__(16) unsigned short Bs[TN * 64];

    const int tid = threadIdx.x;
    const int wave = tid >> 6, lane = tid & 63;
    const int quad = lane >> 4, l16 = lane & 15;
    const int wm = wave >> 1, wn = wave & 1;
    const int bm = blockIdx.y * TM, bn = blockIdx.x * TN;
    const int sub = lane >> 3;
    const int cpr = (lane & 7) ^ sub;

    f32x4 acc[RM][RN];
#pragma unroll
    for (int i = 0; i < RM; i++)
#pragma unroll
        for (int j = 0; j < RN; j++) acc[i][j] = (f32x4){0.f, 0.f, 0.f, 0.f};

    for (int k0 = 0; k0 < K; k0 += 64) {
        __syncthreads();
#pragma unroll
        for (int i = 0; i < AI; i++) {
            int r0 = (wave * AI + i) * 8;
            const unsigned short* g = A + (size_t)(bm + r0 + sub) * K + k0 + cpr * 8;
            __builtin_amdgcn_global_load_lds((GVoid*)g, (LVoid*)&As[r0 * 64], 16, 0, 0);
        }
#pragma unroll
        for (int i = 0; i < BI; i++) {
            int r0 = (wave * BI + i) * 8;
            const unsigned short* g = W + (size_t)(bn + r0 + sub) * K + k0 + cpr * 8;
            __builtin_amdgcn_global_load_lds((GVoid*)g, (LVoid*)&Bs[r0 * 64], 16, 0, 0);
        }
        __syncthreads();
#pragma unroll
        for (int h = 0; h < 2; h++) {
            bf16x8 af[RM], bf[RN];
#pragma unroll
            for (int i = 0; i < RM; i++) {
                int r = wm * WTM + i * 16 + l16;
                int ch = (h * 4 + quad) ^ (r & 7);
                af[i] = *(const bf16x8*)&As[r * 64 + ch * 8];
            }
#pragma unroll
            for (int j = 0; j < RN; j++) {
                int r = wn * WTN + j * 16 + l16;
                int ch = (h * 4 + quad) ^ (r & 7);
                bf[j] = *(const bf16x8*)&Bs[r * 64 + ch * 8];
            }
#pragma unroll
            for (int i = 0; i < RM; i++)
#pragma unroll
                for (int j = 0; j < RN; j++)
                    acc[i][j] = __builtin_amdgcn_mfma_f32_16x16x32_bf16(af[i], bf[j], acc[i][j], 0, 0, 0);
        }
    }

#pragma unroll
    for (int i = 0; i < RM; i++) {
#pragma unroll
        for (int j = 0; j < RN; j++) {
            int c = bn + wn * WTN + j * 16 + l16;
            float bv = HAS_BIAS ? bias[c] : 0.f;
#pragma unroll
            for (int reg = 0; reg < 4; reg++) {
                int r = bm + wm * WTM + i * 16 + quad * 4 + reg;
                if (r < M) {
                    float v = acc[i][j][reg] + bv;
                    if (ACT_GELU) v = gelu_exact(v);
                    if (FLAGS) v *= rowflag[r >> 5];
                    if (OUT_BF16)
                        ((unsigned short*)Cv)[(size_t)r * N + c] = f2bf(v);
                    else
                        ((float*)Cv)[(size_t)r * N + c] = v;
                }
            }
        }
    }
}

// ---------------------------------------------------------------------------
// Merged proj + wfuse GEMM dispatch (proven in R10).
// Tiles 0..503: proj = rel_emb_bf @ rp_w^T + rp_b (f32 out, M=2000 guard, K=768)
// Tiles 504..759: wfuse_z = ow_z @ vwT_z^T (bf16 out, K=512), z = 0,1
// ---------------------------------------------------------------------------
__global__ __launch_bounds__(256) void projwfuse_kernel(
        const unsigned short* __restrict__ rel_bf, const unsigned short* __restrict__ rpw_bf,
        const float* __restrict__ rp_b, float* __restrict__ proj,
        const unsigned short* __restrict__ ow_bf, const unsigned short* __restrict__ vwT_bf,
        unsigned short* __restrict__ wfuse) {
    __shared__ __align__(16) unsigned short As[32 * 64];
    __shared__ __align__(16) unsigned short Bs[64 * 64];

    const unsigned short *A, *W;
    const float* bias;
    int Mg, Kg, bm, bn, obf;
    void* C;
    int t = blockIdx.x;
    if (t < 504) {
        A = rel_bf; W = rpw_bf; bias = rp_b; Mg = R_; Kg = RD_;
        C = proj; obf = 0; bn = (t & 7) * 64; bm = (t >> 3) * 32;
    } else {
        int u = t - 504, z = u >> 7, uu = u & 127;
        A = ow_bf + (size_t)z * 262144; W = vwT_bf + (size_t)z * 262144;
        bias = nullptr; Mg = 512; Kg = 512;
        C = wfuse + (size_t)z * 262144; obf = 1; bn = (uu & 7) * 64; bm = (uu >> 3) * 32;
    }

    const int tid = threadIdx.x;
    const int wave = tid >> 6, lane = tid & 63;
    const int quad = lane >> 4, l16 = lane & 15;
    const int wm = wave >> 1, wn = wave & 1;
    const int sub = lane >> 3;
    const int cpr = (lane & 7) ^ sub;

    f32x4 acc[2];
    acc[0] = (f32x4){0.f, 0.f, 0.f, 0.f};
    acc[1] = (f32x4){0.f, 0.f, 0.f, 0.f};

    for (int k0 = 0; k0 < Kg; k0 += 64) {
        __syncthreads();
        {
            int r0 = wave * 8;
            const unsigned short* g = A + (size_t)(bm + r0 + sub) * Kg + k0 + cpr * 8;
            __builtin_amdgcn_global_load_lds((GVoid*)g, (LVoid*)&As[r0 * 64], 16, 0, 0);
        }
#pragma unroll
        for (int i = 0; i < 2; i++) {
            int r0 = (wave * 2 + i) * 8;
            const unsigned short* g = W + (size_t)(bn + r0 + sub) * Kg + k0 + cpr * 8;
            __builtin_amdgcn_global_load_lds((GVoid*)g, (LVoid*)&Bs[r0 * 64], 16, 0, 0);
        }
        __syncthreads();
#pragma unroll
        for (int h = 0; h < 2; h++) {
            bf16x8 af, bf[2];
            {
                int r = wm * 16 + l16;
                int ch = (h * 4 + quad) ^ (r & 7);
                af = *(const bf16x8*)&As[r * 64 + ch * 8];
            }
#pragma unroll
            for (int j = 0; j < 2; j++) {
                int r = wn * 32 + j * 16 + l16;
                int ch = (h * 4 + quad) ^ (r & 7);
                bf[j] = *(const bf16x8*)&Bs[r * 64 + ch * 8];
            }
#pragma unroll
            for (int j = 0; j < 2; j++)
                acc[j] = __builtin_amdgcn_mfma_f32_16x16x32_bf16(af, bf[j], acc[j], 0, 0, 0);
        }
    }

#pragma unroll
    for (int j = 0; j < 2; j++) {
        int c = bn + wn * 32 + j * 16 + l16;
        float bv = bias ? bias[c] : 0.f;
#pragma unroll
        for (int reg = 0; reg < 4; reg++) {
            int r = bm + wm * 16 + quad * 4 + reg;
            if (r < Mg) {
                float v = acc[j][reg] + bv;
                if (obf)
                    ((unsigned short*)C)[(size_t)r * 512 + c] = f2bf(v);
                else
                    ((float*)C)[(size_t)r * 512 + c] = v;
            }
        }
    }
}

// ---------------------------------------------------------------------------
// prep_all: one launch for all input-only preprocessing (R8-proven).
// ---------------------------------------------------------------------------
struct PrepArgs {
    const float* src[9];
    unsigned short* dst[9];
    int cum4[10];
    int nb_cvt, total4;
    const float* ly_vw; unsigned short* vwT;
    const float* ly_ow; const float* ly_vb; const float* ly_ob; float* bfuse;
    const float* t_kb; const float* t_vb; float* kvb;
    const float* edge_mask; float* flags;
    const float* mem_q; const float* t_qw; const float* t_qb; float* qbuf;
};

__global__ __launch_bounds__(256) void prep_all(PrepArgs a) {
    int bx = blockIdx.x, tid = threadIdx.x;
    if (bx < a.nb_cvt) {
        int i = bx * 256 + tid;
        if (i < a.total4) {
            int k = 0;
#pragma unroll
            for (int j = 0; j < 8; j++) if (i >= a.cum4[j + 1]) k = j + 1;
            int o = i - a.cum4[k];
            float4 v = ((const float4*)a.src[k])[o];
            ushort4 u;
            u.x = f2bf(v.x); u.y = f2bf(v.y); u.z = f2bf(v.z); u.w = f2bf(v.w);
            ((ushort4*)a.dst[k])[o] = u;
        }
        return;
    }
    bx -= a.nb_cvt;
    if (bx < 512) {                            // vw transpose+convert
        __shared__ float tile[32][33];
        int l = bx >> 8, t16 = bx & 255;
        int j0 = (t16 >> 4) * 32, k0 = (t16 & 15) * 32;
        int tx = tid & 31, ty = tid >> 5;
        const float* src = a.ly_vw + (size_t)l * 512 * 512;
        for (int r = ty; r < 32; r += 8)
            tile[r][tx] = src[(size_t)(j0 + r) * 512 + k0 + tx];
        __syncthreads();
        unsigned short* dst = a.vwT + (size_t)l * 512 * 512;
        for (int r = ty; r < 32; r += 8)
            dst[(size_t)(k0 + r) * 512 + j0 + tx] = f2bf(tile[tx][r]);
        return;
    }
    bx -= 512;
    if (bx < 256) {                            // bfuse wave-dots
        int wid = bx * 4 + (tid >> 6);
        int z = wid >> 9, n = wid & 511, lane = tid & 63;
        const float* owr = a.ly_ow + (size_t)z * 512 * 512 + (size_t)n * 512;
        const float* vbr = a.ly_vb + (size_t)z * 512;
        float s = 0.f;
#pragma unroll
        for (int j = 0; j < 8; j++) s += owr[lane + 64 * j] * vbr[lane + 64 * j];
#pragma unroll
        for (int off = 32; off; off >>= 1) s += __shfl_xor(s, off, 64);
        if (lane == 0) a.bfuse[z * 512 + n] = s + a.ly_ob[z * 512 + n];
        return;
    }
    bx -= 256;
    if (bx < 1) {                              // kvb + flags
        __shared__ float red[4];
        for (int n = tid; n < 512; n += 256) {
            a.kvb[n] = a.t_kb[n];
            a.kvb[n + 512] = a.t_vb[n];
        }
        for (int b = 0; b < B_; b++) {
            float s = a.edge_mask[b * E_ + tid];
#pragma unroll
            for (int off = 32; off; off >>= 1) s += __shfl_xor(s, off, 64);
            if ((tid & 63) == 0) red[tid >> 6] = s;
            __syncthreads();
            if (tid == 0)
                a.flags[b] = (red[0] + red[1] + red[2] + red[3] == 0.f) ? 0.f : 1.f;
            __syncthreads();
        }
        return;
    }
    bx -= 1;
    {                                          // q-proj wave-dots
        int wid = bx * 4 + (tid >> 6);
        int m = wid >> 9, n = wid & 511, lane = tid & 63;
        const float* ar = a.mem_q + (size_t)m * 512;
        const float* br = a.t_qw + (size_t)n * 512;
        float s = 0.f;
#pragma unroll
        for (int j = 0; j < 8; j++) s += ar[lane + 64 * j] * br[lane + 64 * j];
#pragma unroll
        for (int off = 32; off; off >>= 1) s += __shfl_xor(s, off, 64);
        if (lane == 0) a.qbuf[(size_t)m * 512 + n] = s + a.t_qb[n];
    }
}

// Per-edge cosine sims (norms inline) -> wave-parallel top-8 -> mean agg.
__global__ void sim_topk_agg(const int* __restrict__ eids, const int* __restrict__ nids,
                             const float* __restrict__ proj,
                             unsigned short* __restrict__ agg_bf, float* __restrict__ states) {
    int be = blockIdx.x, tid = threadIdx.x;
    __shared__ float ev[512];
    __shared__ float sims[32];
    __shared__ int nid_s[32];
    __shared__ int sel[8];

    int eid = eids[be];
    const float* ep = proj + (size_t)eid * D_;
    float e0 = ep[tid], e1 = ep[tid + 256];
    ev[tid] = e0; ev[tid + 256] = e1;
    states[(size_t)be * D_ + tid] = e0;
    states[(size_t)be * D_ + tid + 256] = e1;
    if (tid < 32) nid_s[tid] = nids[be * N_ + tid];
    __syncthreads();

    int wid = tid >> 6, lane = tid & 63;
    float se = 0.f;
#pragma unroll
    for (int j = 0; j < 8; j++) { float v = ev[lane + 64 * j]; se += v * v; }
#pragma unroll
    for (int off = 32; off; off >>= 1) se += __shfl_xor(se, off, 64);
    float en = fmaxf(sqrtf(se), 1e-12f);

    for (int n = wid; n < N_; n += 4) {
        int nid = nid_s[n];
        const float* np = proj + (size_t)nid * D_;
        float s = 0.f, s2 = 0.f;
#pragma unroll
        for (int j = 0; j < 8; j++) {
            float v = np[lane + 64 * j];
            s += v * ev[lane + 64 * j];
            s2 += v * v;
        }
#pragma unroll
        for (int off = 32; off; off >>= 1) {
            s += __shfl_xor(s, off, 64);
            s2 += __shfl_xor(s2, off, 64);
        }
        if (lane == 0) sims[n] = s / (fmaxf(sqrtf(s2), 1e-12f) * en);
    }
    __syncthreads();

    if (tid < 64) {                            // wave-parallel top-8 (lax.top_k order)
        float v = (tid < 32) ? sims[tid] : -3.402823466e38f;
        int idx = tid;
        for (int k = 0; k < K_; k++) {
            float bv = v; int bi = idx;
#pragma unroll
            for (int off = 32; off; off >>= 1) {
                float ov = __shfl_xor(bv, off, 64);
                int oi = __shfl_xor(bi, off, 64);
                if (ov > bv || (ov == bv && oi < bi)) { bv = ov; bi = oi; }
            }
            if (tid == 0) sel[k] = nid_s[bi];
            if (idx == bi) v = -3.402823466e38f;
        }
    }
    __syncthreads();

    float a0 = 0.f, a1 = 0.f;
#pragma unroll
    for (int k = 0; k < K_; k++) {
        const float* sp = proj + (size_t)sel[k] * D_;
        a0 += sp[tid]; a1 += sp[tid + 256];
    }
    agg_bf[(size_t)be * D_ + tid] = f2bf(a0 * 0.125f);
    agg_bf[(size_t)be * D_ + tid + 256] = f2bf(a1 * 0.125f);
}

// out = LN(x + y)*g + b (optional *mask); y has row stride ystride. (R8-proven)
__global__ void add_ln_kernel(const float* __restrict__ x, const float* __restrict__ y,
                              int ystride, const float* __restrict__ g,
                              const float* __restrict__ bb, const float* __restrict__ mask,
                              float* __restrict__ out, unsigned short* __restrict__ out_bf) {
    int t = blockIdx.x, tid = threadIdx.x;
    const float* xr = x + (size_t)t * D_;
    const float* yr = y + (size_t)t * ystride;
    float x0 = xr[tid] + yr[tid];
    float x1 = xr[tid + 256] + yr[tid + 256];
    __shared__ float red[8];
    float s = x0 + x1;
#pragma unroll
    for (int off = 32; off; off >>= 1) s += __shfl_xor(s, off, 64);
    int wid = tid >> 6;
    if ((tid & 63) == 0) red[wid] = s;
    __syncthreads();
    float mean = (red[0] + red[1] + red[2] + red[3]) * (1.f / 512.f);
    float d0 = x0 - mean, d1 = x1 - mean;
    float v = d0 * d0 + d1 * d1;
#pragma unroll
    for (int off = 32; off; off >>= 1) v += __shfl_xor(v, off, 64);
    if ((tid & 63) == 0) red[4 + wid] = v;
    __syncthreads();
    float var = (red[4] + red[5] + red[6] + red[7]) * (1.f / 512.f);
    float rs = rsqrtf(var + 1e-5f);
    float mv = mask ? mask[t] : 1.f;
    float o0 = (d0 * rs * g[tid] + bb[tid]) * mv;
    float o1 = (d1 * rs * g[tid + 256] + bb[tid + 256]) * mv;
    out[(size_t)t * D_ + tid] = o0;
    out[(size_t)t * D_ + tid + 256] = o1;
    out_bf[(size_t)t * D_ + tid] = f2bf(o0);
    out_bf[(size_t)t * D_ + tid + 256] = f2bf(o1);
}

// Double LN: s3 = LN( (LN(x+y)*g2+b2)*mask + att ) * g1 + b1.
// Row-local chain of LN2(l0) and LN1(l1) — same reduction pattern as two
// add_ln kernels, zero redundant work. grid = T, block 256.
__global__ void dbl_ln_kernel(const float* __restrict__ x, const float* __restrict__ y,
                              const float* __restrict__ g2, const float* __restrict__ b2,
                              const float* __restrict__ mask,
                              const float* __restrict__ att, int astride,
                              const float* __restrict__ g1, const float* __restrict__ b1,
                              float* __restrict__ out, unsigned short* __restrict__ out_bf) {
    int t = blockIdx.x, tid = threadIdx.x;
    const float* xr = x + (size_t)t * D_;
    const float* yr = y + (size_t)t * D_;
    float x0 = xr[tid] + yr[tid];
    float x1 = xr[tid + 256] + yr[tid + 256];
    __shared__ float red[8];
    int wid = tid >> 6;
    // LN #1 (= LN2 of layer 0)
    float s = x0 + x1;
#pragma unroll
    for (int off = 32; off; off >>= 1) s += __shfl_xor(s, off, 64);
    if ((tid & 63) == 0) red[wid] = s;
    __syncthreads();
    float mean = (red[0] + red[1] + red[2] + red[3]) * (1.f / 512.f);
    float d0 = x0 - mean, d1 = x1 - mean;
    float v = d0 * d0 + d1 * d1;
#pragma unroll
    for (int off = 32; off; off >>= 1) v += __shfl_xor(v, off, 64);
    if ((tid & 63) == 0) red[4 + wid] = v;
    __syncthreads();
    float var = (red[4] + red[5] + red[6] + red[7]) * (1.f / 512.f);
    float rs = rsqrtf(var + 1e-5f);
    float mv = mask[t];
    float t0 = (d0 * rs * g2[tid] + b2[tid]) * mv;
    float t1 = (d1 * rs * g2[tid + 256] + b2[tid + 256]) * mv;
    // residual with layer-1 attention
    const float* ar = att + (size_t)t * astride;
    float y0 = t0 + ar[tid];
    float y1 = t1 + ar[tid + 256];
    __syncthreads();
    // LN #2 (= LN1 of layer 1)
    float s2 = y0 + y1;
#pragma unroll
    for (int off = 32; off; off >>= 1) s2 += __shfl_xor(s2, off, 64);
    if ((tid & 63) == 0) red[wid] = s2;
    __syncthreads();
    float mean2 = (red[0] + red[1] + red[2] + red[3]) * (1.f / 512.f);
    float e0 = y0 - mean2, e1 = y1 - mean2;
    float v2 = e0 * e0 + e1 * e1;
#pragma unroll
    for (int off = 32; off; off >>= 1) v2 += __shfl_xor(v2, off, 64);
    if ((tid & 63) == 0) red[4 + wid] = v2;
    __syncthreads();
    float var2 = (red[4] + red[5] + red[6] + red[7]) * (1.f / 512.f);
    float rs2 = rsqrtf(var2 + 1e-5f);
    float o0 = e0 * rs2 * g1[tid] + b1[tid];
    float o1 = e1 * rs2 * g1[tid + 256] + b1[tid + 256];
    out[(size_t)t * D_ + tid] = o0;
    out[(size_t)t * D_ + tid + 256] = o1;
    out_bf[(size_t)t * D_ + tid] = f2bf(o0);
    out_bf[(size_t)t * D_ + tid + 256] = f2bf(o1);
}

// Cross-attention over combined kv [T,1024]. grid = B_*M_*H_ (b in low bits).
__global__ void mem_attn(const float* __restrict__ qb, const float* __restrict__ kv,
                         const float* __restrict__ mask, unsigned short* __restrict__ memb) {
    int idx = blockIdx.x;
    int b = idx & 7;
    int h = (idx >> 3) & 7;
    int m = idx >> 6;
    int tid = threadIdx.x;
    __shared__ float qh[64];
    __shared__ float sc[256];
    __shared__ float red[8];
    __shared__ float oacc[4][64];

    float mk = mask[b * E_ + tid];
    if (tid < 64) qh[tid] = qb[m * D_ + h * DH_ + tid];
    __syncthreads();
    const float* kr = kv + ((size_t)(b * E_ + tid)) * 1024 + h * DH_;
    float s = 0.f;
#pragma unroll
    for (int d = 0; d < DH_; d += 4) {
        float4 k4 = *(const float4*)(kr + d);
        s += k4.x * qh[d] + k4.y * qh[d + 1] + k4.z * qh[d + 2] + k4.w * qh[d + 3];
    }
    s *= 0.125f;
    if (mk == 0.f) s = -3.402823466e38f;
    float mx = s;
#pragma unroll
    for (int off = 32; off; off >>= 1) mx = fmaxf(mx, __shfl_xor(mx, off, 64));
    if ((tid & 63) == 0) red[tid >> 6] = mx;
    __syncthreads();
    mx = fmaxf(fmaxf(red[0], red[1]), fmaxf(red[2], red[3]));
    float p = expf(s - mx);
    float sum = p;
#pragma unroll
    for (int off = 32; off; off >>= 1) sum += __shfl_xor(sum, off, 64);
    if ((tid & 63) == 0) red[4 + (tid >> 6)] = sum;
    __syncthreads();
    sum = red[4] + red[5] + red[6] + red[7];
    sc[tid] = p / sum;
    __syncthreads();
    int d = tid & 63, part = tid >> 6;
    const float* vcol = kv + ((size_t)(b * E_ + part * 64)) * 1024 + 512 + h * DH_ + d;
    float acc = 0.f;
#pragma unroll 8
    for (int e = 0; e < 64; e++) acc += sc[part * 64 + e] * vcol[(size_t)e * 1024];
    oacc[part][d] = acc;
    __syncthreads();
    if (part == 0)
        memb[((size_t)(b * M_ + m)) * D_ + h * DH_ + d] =
            f2bf(oacc[0][d] + oacc[1][d] + oacc[2][d] + oacc[3][d]);
}

extern "C" void kernel_launch(void* const* d_in, const int* in_sizes, int n_in,
                              void* d_out, int out_size, void* d_ws, size_t ws_size,
                              hipStream_t stream) {
    const int*   edge_rel_ids     = (const int*)d_in[0];
    const int*   neighbor_rel_ids = (const int*)d_in[1];
    const float* edge_mask        = (const float*)d_in[2];
    const float* rel_emb          = (const float*)d_in[3];
    const float* rp_w             = (const float*)d_in[4];
    const float* rp_b             = (const float*)d_in[5];
    const float* ly_vw            = (const float*)d_in[6];
    const float* ly_vb            = (const float*)d_in[7];
    const float* ly_ow            = (const float*)d_in[8];
    const float* ly_ob            = (const float*)d_in[9];
    const float* ly_n1g           = (const float*)d_in[10];
    const float* ly_n1b           = (const float*)d_in[11];
    const float* ly_n2g           = (const float*)d_in[12];
    const float* ly_n2b           = (const float*)d_in[13];
    const float* ly_w1            = (const float*)d_in[14];
    const float* ly_b1            = (const float*)d_in[15];
    const float* ly_w2            = (const float*)d_in[16];
    const float* ly_b2            = (const float*)d_in[17];
    const float* mem_q            = (const float*)d_in[18];
    const float* t_qw             = (const float*)d_in[19];
    const float* t_qb             = (const float*)d_in[20];
    const float* t_kw             = (const float*)d_in[21];
    const float* t_kb             = (const float*)d_in[22];
    const float* t_vw             = (const float*)d_in[23];
    const float* t_vb             = (const float*)d_in[24];
    const float* t_ow             = (const float*)d_in[25];
    const float* t_ob             = (const float*)d_in[26];
    const float* proj_w           = (const float*)d_in[27];
    const float* proj_b           = (const float*)d_in[28];
    float* out = (float*)d_out;
    (void)ws_size; (void)in_sizes; (void)n_in; (void)out_size;

    char* ws = (char*)d_ws;
    size_t off = 0;
    auto allocf = [&](size_t n) { float* p = (float*)(ws + off); off += ((n * 4 + 255) & ~(size_t)255); return p; };
    auto allocb = [&](size_t n) { unsigned short* p = (unsigned short*)(ws + off); off += ((n * 2 + 255) & ~(size_t)255); return p; };

    const int T = B_ * E_;

    float* states  = allocf((size_t)T * D_);   // states0, later states3
    float* statesX = allocf((size_t)T * D_);   // states1, later states4
    float* proj    = allocf((size_t)R_ * D_);
    float* tmpB    = allocf((size_t)T * D_);
    float* attnall = allocf((size_t)T * 2 * D_);
    float* qbuf    = allocf((size_t)M_ * D_);
    float* bfuse   = allocf(2 * D_);
    float* kvb     = allocf(2 * D_);
    float* flags   = allocf(B_);
    float* kvbuf   = attnall;   // alias: attnall dead after dbl_ln consumed l1 slice

    unsigned short* rel_bf  = allocb((size_t)2048 * RD_);   // rows padded to 2048
    unsigned short* rpw_bf  = allocb((size_t)D_ * RD_);
    unsigned short* agg_bf  = allocb((size_t)T * D_);
    unsigned short* st_bf   = allocb((size_t)T * D_);
    unsigned short* ff1_bf  = allocb((size_t)T * 4 * D_);
    unsigned short* vwT_bf  = allocb((size_t)L_ * D_ * D_);
    unsigned short* ow_bf   = allocb((size_t)L_ * D_ * D_);
    unsigned short* wfuse   = allocb((size_t)L_ * D_ * D_);
    unsigned short* w1_bf   = allocb((size_t)L_ * 4 * D_ * D_);
    unsigned short* w2_bf   = allocb((size_t)L_ * 4 * D_ * D_);
    unsigned short* kvw_bf  = allocb((size_t)2 * D_ * D_);
    unsigned short* tow_bf  = allocb((size_t)D_ * D_);
    unsigned short* pw_bf   = allocb((size_t)HL_ * D_);
    unsigned short* memb_bf = allocb((size_t)B_ * M_ * D_);
    unsigned short* mem2_bf = allocb((size_t)B_ * M_ * D_);

    // ---- 1. prep ----
    PrepArgs a;
    int sizes[9] = { R_ * RD_, D_ * RD_, L_ * D_ * D_, L_ * 4 * D_ * D_,
                     L_ * 4 * D_ * D_, D_ * D_, D_ * D_, D_ * D_, HL_ * D_ };
    const float* srcs[9] = { rel_emb, rp_w, ly_ow, ly_w1, ly_w2, t_kw, t_vw, t_ow, proj_w };
    unsigned short* dsts[9] = { rel_bf, rpw_bf, ow_bf, w1_bf, w2_bf,
                                kvw_bf, kvw_bf + (size_t)D_ * D_, tow_bf, pw_bf };
    int cum = 0;
    for (int i = 0; i < 9; i++) {
        a.src[i] = srcs[i]; a.dst[i] = dsts[i];
        a.cum4[i] = cum; cum += sizes[i] / 4;
    }
    a.cum4[9] = cum;
    a.total4 = cum;
    a.nb_cvt = (cum + 255) / 256;
    a.ly_vw = ly_vw; a.vwT = vwT_bf;
    a.ly_ow = ly_ow; a.ly_vb = ly_vb; a.ly_ob = ly_ob; a.bfuse = bfuse;
    a.t_kb = t_kb; a.t_vb = t_vb; a.kvb = kvb;
    a.edge_mask = edge_mask; a.flags = flags;
    a.mem_q = mem_q; a.t_qw = t_qw; a.t_qb = t_qb; a.qbuf = qbuf;
    int nblk = a.nb_cvt + 512 + 256 + 1 + 4096;
    prep_all<<<nblk, 256, 0, stream>>>(a);

    // ---- 2. proj + wfuse merged ----
    projwfuse_kernel<<<760, 256, 0, stream>>>(rel_bf, rpw_bf, rp_b, proj,
                                              ow_bf, vwT_bf, wfuse);

    // ---- 3. sims + top-k + aggregate + states0 init ----
    sim_topk_agg<<<T, 256, 0, stream>>>(edge_rel_ids, neighbor_rel_ids, proj,
                                        agg_bf, states);

    // ---- 4. attn (both layers) = agg @ wfuse^T + bfuse  [2048,1024] ----
    gemm_mfma<64, 64, 0, 0, 1, 0><<<dim3(16, 32), 256, 0, stream>>>(
        agg_bf, wfuse, bfuse, attnall, T, 2 * D_, D_, nullptr);

    // ---- 5. LN1(l0): states1 = LN(states0 + attnall_l0) ----
    add_ln_kernel<<<T, 256, 0, stream>>>(states, attnall, 2 * D_,
                                         ly_n1g, ly_n1b, nullptr, statesX, st_bf);
    // ---- 6. ff1(l0) ----
    gemm_mfma<64, 64, 1, 1, 1, 0><<<dim3(32, 32), 256, 0, stream>>>(
        st_bf, w1_bf, ly_b1, ff1_bf, T, 4 * D_, D_, nullptr);
    // ---- 7. ff2(l0) ----
    gemm_mfma<32, 64, 0, 0, 1, 0><<<dim3(8, 64), 256, 0, stream>>>(
        ff1_bf, w2_bf, ly_b2, tmpB, T, D_, 4 * D_, nullptr);
    // ---- 8. LN2(l0)+LN1(l1) fused: states3 = LN(LN(states1+ff)*mask + attn_l1) ----
    dbl_ln_kernel<<<T, 256, 0, stream>>>(statesX, tmpB, ly_n2g, ly_n2b, edge_mask,
                                         attnall + D_, 2 * D_, ly_n1g + D_, ly_n1b + D_,
                                         states, st_bf);
    // ---- 9. ff1(l1) ----
    gemm_mfma<64, 64, 1, 1, 1, 0><<<dim3(32, 32), 256, 0, stream>>>(
        st_bf, w1_bf + (size_t)4 * D_ * D_, ly_b1 + 4 * D_, ff1_bf, T, 4 * D_, D_, nullptr);
    // ---- 10. ff2(l1) ----
    gemm_mfma<32, 64, 0, 0, 1, 0><<<dim3(8, 64), 256, 0, stream>>>(
        ff1_bf, w2_bf + (size_t)4 * D_ * D_, ly_b2 + D_, tmpB, T, D_, 4 * D_, nullptr);
    // ---- 11. LN2(l1): states4 = LN(states3 + ff)*mask ----
    add_ln_kernel<<<T, 256, 0, stream>>>(states, tmpB, D_,
                                         ly_n2g + D_, ly_n2b + D_, edge_mask,
                                         statesX, st_bf);
    // ---- 12. kv projection [2048,1024] ----
    gemm_mfma<64, 64, 0, 0, 1, 0><<<dim3(16, 32), 256, 0, stream>>>(
        st_bf, kvw_bf, kvb, kvbuf, T, 2 * D_, D_, nullptr);
    // ---- 13. memory cross-attention ----
    mem_attn<<<B_ * M_ * H_, 256, 0, stream>>>(qbuf, kvbuf, edge_mask, memb_bf);
    // ---- 14. t_ow projection + no-edge zeroing via flags ----
    gemm_mfma<32, 64, 0, 1, 1, 1><<<dim3(8, 8), 256, 0, stream>>>(
        memb_bf, tow_bf, t_ob, mem2_bf, B_ * M_, D_, D_, flags);
    // ---- 15. final LLM projection ----
    gemm_mfma<32, 64, 0, 0, 1, 0><<<dim3(64, 8), 256, 0, stream>>>(
        mem2_bf, pw_bf, proj_b, out, B_ * M_, HL_, D_, nullptr);
}